// Round 5
// baseline (154.434 us; speedup 1.0000x reference)
//
#include <hip/hip_runtime.h>
#include <hip/hip_bf16.h>

typedef __attribute__((ext_vector_type(8))) short short8;
typedef __attribute__((ext_vector_type(4))) short short4v;
typedef __attribute__((ext_vector_type(4))) float floatx4;

#define BDIM 128
#define RDIM 1024
#define NB   4096
#define NG   16
#define LDP  40     // proven LDS stride (80 B)

__device__ __forceinline__ float mishf(float x) {
    float e = __expf(x);
    float t = e * (e + 2.0f);
    float r = x * (t / (t + 2.0f));
    return x > 20.0f ? x : r;
}

__device__ __forceinline__ short8 cvt8v(float4 f0, float4 f1) {
    union { __hip_bfloat162 h; unsigned u; } c0, c1, c2, c3;
    c0.h = __float22bfloat162_rn(make_float2(f0.x, f0.y));
    c1.h = __float22bfloat162_rn(make_float2(f0.z, f0.w));
    c2.h = __float22bfloat162_rn(make_float2(f1.x, f1.y));
    c3.h = __float22bfloat162_rn(make_float2(f1.z, f1.w));
    union { short8 s; unsigned u[4]; } r;
    r.u[0] = c0.u; r.u[1] = c1.u; r.u[2] = c2.u; r.u[3] = c3.u;
    return r.s;
}

__device__ __forceinline__ short4v cvt4v(float4 f) {
    union { __hip_bfloat162 h; unsigned u; } c0, c1;
    c0.h = __float22bfloat162_rn(make_float2(f.x, f.y));
    c1.h = __float22bfloat162_rn(make_float2(f.z, f.w));
    union { short4v s; unsigned u[2]; } r;
    r.u[0] = c0.u; r.u[1] = c1.u;
    return r.s;
}

// async global->LDS, 16B per lane, LDS dest = wave-uniform base + lane*16
__device__ __forceinline__ void gld16(const void* g, void* l) {
    __builtin_amdgcn_global_load_lds(
        (const __attribute__((address_space(1))) unsigned int*)g,
        (__attribute__((address_space(3))) unsigned int*)l, 16, 0, 0);
}

#define MFMA(a, b, c) __builtin_amdgcn_mfma_f32_16x16x32_bf16(a, b, c, 0, 0, 0)

// region boundaries (floats) for the flat conversion pass
#define C1       4194304u   // RF 4096*1024
#define C2       5242880u   // +Wrfrf 1024*1024
#define C3       5373952u   // +Wrfbb 128*1024
#define C4       5505024u   // +Wbbrf 1024*128
#define CT       5521408u   // +Wbbbb 128*128
#define FLATB    1536

// ---------------- prep: BB mean + one-time fp32->bf16 of all GEMM operands ----------------
__global__ void __launch_bounds__(256) k_prep(
    const float* __restrict__ bb, const float* __restrict__ rf,
    const float* __restrict__ Wrfrf, const float* __restrict__ Wrfbb,
    const float* __restrict__ Wbbrf, const float* __restrict__ Wbbbb,
    short* __restrict__ bb_b, short* __restrict__ mean_b, short* __restrict__ rf_b,
    short* __restrict__ wrfrf_b, short* __restrict__ wrfbb_b,
    short* __restrict__ wbbrf_b, short* __restrict__ wbbbb_b)
{
    int bid = blockIdx.x;
    int tid = threadIdx.x;
    if (bid < 512) {
        // mean over G + bf16 copy of BB
        int b = bid * 8 + (tid >> 5);
        int d = (tid & 31) * 4;
        const float4* p = (const float4*)(bb + (size_t)b * (NG * BDIM) + d);
        short* ob = bb_b + (size_t)b * (NG * BDIM) + d;
        float4 s = {0.f, 0.f, 0.f, 0.f};
        #pragma unroll
        for (int g = 0; g < NG; ++g) {
            float4 v = p[g * (BDIM / 4)];
            s.x += v.x; s.y += v.y; s.z += v.z; s.w += v.w;
            *(short4v*)(ob + g * BDIM) = cvt4v(v);
        }
        s.x *= 0.0625f; s.y *= 0.0625f; s.z *= 0.0625f; s.w *= 0.0625f;
        *(short4v*)(mean_b + (size_t)b * BDIM + d) = cvt4v(s);
    } else {
        // flat fp32->bf16 over RF + 4 weights (all region sizes multiples of 8)
        size_t t = (size_t)(bid - 512) * 256 + tid;
        for (size_t base = t * 8; base < CT; base += (size_t)FLATB * 256 * 8) {
            const float* s; short* dst; size_t off;
            if (base < C1)      { s = rf;    dst = rf_b;    off = base; }
            else if (base < C2) { s = Wrfrf; dst = wrfrf_b; off = base - C1; }
            else if (base < C3) { s = Wrfbb; dst = wrfbb_b; off = base - C2; }
            else if (base < C4) { s = Wbbrf; dst = wbbrf_b; off = base - C3; }
            else                { s = Wbbbb; dst = wbbbb_b; off = base - C4; }
            float4 f0 = ((const float4*)(s + off))[0];
            float4 f1 = ((const float4*)(s + off))[1];
            *(short8*)(dst + off) = cvt8v(f0, f1);
        }
    }
}

// ---- new_RF = mish(RF@Wrfrf^T+b1) + mish(mean@Wbbrf^T+b2); rf2bb = mish(RF@Wrfbb^T+b3) ----
// 64x64 tiles, merged N-panel (Wrfrf 1024 ++ Wrfbb 128 = 1152 cols), grid 64x18 = 1152
// blocks (~4.5 blocks/CU resident vs 2 before: the occupancy fix). 4 waves, each 32x32.
// Proven Round-0 reg->LDS dbuf pipeline (loads 2 iters ahead stay in flight across
// barriers), BK=32, LDP=40, LDS 20.5 KB. Bijective XCD swizzle (1152 = 8*144).
__global__ void __launch_bounds__(256) k_newrf(
    const short* __restrict__ rfb,     // [4096,1024] bf16
    const short* __restrict__ meanb,   // [4096,128]  bf16
    const short* __restrict__ wrfrfb,  // [1024,1024] bf16
    const float* __restrict__ brfrf,
    const short* __restrict__ wbbrfb,  // [1024,128]  bf16
    const float* __restrict__ bbbrf,
    const short* __restrict__ wrfbbb,  // [128,1024]  bf16
    const float* __restrict__ brfbb,
    float* __restrict__ out,           // [4096,1024]
    float* __restrict__ rf2bb)         // [4096,128] fp32 ws
{
    __shared__ short As[2][64 * LDP];
    __shared__ short Bs[2][64 * LDP];
    int tid = threadIdx.x;
    int wave = tid >> 6, lane = tid & 63;
    int r = lane & 15, quad = lane >> 4;
    int wm = (wave & 1) * 32, wn = (wave >> 1) * 32;
    // XCD-contiguous remap: XCD k handles logical blocks [k*144, (k+1)*144)
    int bid = (blockIdx.x & 7) * 144 + (blockIdx.x >> 3);
    int mt = bid / 18, nt = bid % 18;
    int m0 = mt * 64;
    bool isP = (nt >= 16);
    const short* Bsrc = isP ? (wrfbbb + (size_t)(nt - 16) * 64 * RDIM)
                            : (wrfrfb + (size_t)nt * 64 * RDIM);

    int srow = tid >> 2, skq = (tid & 3) * 8;
    int sidx = srow * LDP + skq;
    const short* aG  = rfb  + (size_t)(m0 + srow) * RDIM + skq;
    const short* bG  = Bsrc + (size_t)srow * RDIM + skq;
    const short* a2G = meanb + (size_t)(m0 + srow) * BDIM + skq;
    const short* b2G = wbbrfb + (size_t)(nt * 64 + srow) * BDIM + skq;  // used only if !isP

    floatx4 acc1[2][2], acc2[2][2];
    #pragma unroll
    for (int mi = 0; mi < 2; ++mi) {
        acc1[mi][0] = floatx4{0.f,0.f,0.f,0.f}; acc1[mi][1] = acc1[mi][0];
        acc2[mi][0] = acc1[mi][0]; acc2[mi][1] = acc1[mi][0];
    }

    short8 ra, rb;
    // prologue: tile0 -> buf0; tile1 in regs/in flight
    ra = *(const short8*)aG; rb = *(const short8*)bG;
    *(short8*)&As[0][sidx] = ra; *(short8*)&Bs[0][sidx] = rb;
    ra = *(const short8*)(aG + 32); rb = *(const short8*)(bG + 32);
    __syncthreads();

    for (int it = 0; it < 32; ++it) {
        const short* Ac = As[it & 1];
        const short* Bc = Bs[it & 1];
        short8 af[2], bf[2];
        af[0] = *(const short8*)&Ac[(wm + r) * LDP + quad * 8];
        af[1] = *(const short8*)&Ac[(wm + 16 + r) * LDP + quad * 8];
        bf[0] = *(const short8*)&Bc[(wn + r) * LDP + quad * 8];
        bf[1] = *(const short8*)&Bc[(wn + 16 + r) * LDP + quad * 8];
        acc1[0][0] = MFMA(af[0], bf[0], acc1[0][0]);
        acc1[0][1] = MFMA(af[0], bf[1], acc1[0][1]);
        acc1[1][0] = MFMA(af[1], bf[0], acc1[1][0]);
        acc1[1][1] = MFMA(af[1], bf[1], acc1[1][1]);
        if (it < 31) {
            int nb = (it + 1) & 1;
            *(short8*)&As[nb][sidx] = ra;
            *(short8*)&Bs[nb][sidx] = rb;
        }
        if (it < 30) {
            int k = (it + 2) * 32;
            ra = *(const short8*)(aG + k); rb = *(const short8*)(bG + k);
        } else if (it == 30 && !isP) {
            // prefetch GEMM2 tile0 while GEMM1's last iter computes
            ra = *(const short8*)a2G; rb = *(const short8*)b2G;
        }
        __syncthreads();
    }

    // ---- GEMM2: mean @ Wbbrf^T, K=128 (4 dbuf iters), only for nt<16 ----
    if (!isP) {
        *(short8*)&As[0][sidx] = ra; *(short8*)&Bs[0][sidx] = rb;
        ra = *(const short8*)(a2G + 32); rb = *(const short8*)(b2G + 32);
        __syncthreads();
        for (int it = 0; it < 4; ++it) {
            const short* Ac = As[it & 1];
            const short* Bc = Bs[it & 1];
            short8 af[2], bf[2];
            af[0] = *(const short8*)&Ac[(wm + r) * LDP + quad * 8];
            af[1] = *(const short8*)&Ac[(wm + 16 + r) * LDP + quad * 8];
            bf[0] = *(const short8*)&Bc[(wn + r) * LDP + quad * 8];
            bf[1] = *(const short8*)&Bc[(wn + 16 + r) * LDP + quad * 8];
            acc2[0][0] = MFMA(af[0], bf[0], acc2[0][0]);
            acc2[0][1] = MFMA(af[0], bf[1], acc2[0][1]);
            acc2[1][0] = MFMA(af[1], bf[0], acc2[1][0]);
            acc2[1][1] = MFMA(af[1], bf[1], acc2[1][1]);
            if (it < 3) {
                int nb = (it + 1) & 1;
                *(short8*)&As[nb][sidx] = ra;
                *(short8*)&Bs[nb][sidx] = rb;
            }
            if (it < 2) {
                int k = (it + 2) * 32;
                ra = *(const short8*)(a2G + k); rb = *(const short8*)(b2G + k);
            }
            __syncthreads();
        }
        // epilogue: fused mish(GEMM1)+mish(GEMM2)
        #pragma unroll
        for (int nj = 0; nj < 2; ++nj) {
            int col = nt * 64 + wn + nj * 16 + r;
            float b1 = brfrf[col];
            float b2 = bbbrf[col];
            #pragma unroll
            for (int mi = 0; mi < 2; ++mi) {
                #pragma unroll
                for (int g = 0; g < 4; ++g) {
                    int row = m0 + wm + mi * 16 + quad * 4 + g;
                    out[(size_t)row * RDIM + col] =
                        mishf(acc1[mi][nj][g] + b1) + mishf(acc2[mi][nj][g] + b2);
                }
            }
        }
    } else {
        // P blocks: rf2bb = mish(RF @ Wrfbb^T + b3)
        #pragma unroll
        for (int nj = 0; nj < 2; ++nj) {
            int colL = (nt - 16) * 64 + wn + nj * 16 + r;
            float bs = brfbb[colL];
            #pragma unroll
            for (int mi = 0; mi < 2; ++mi) {
                #pragma unroll
                for (int g = 0; g < 4; ++g) {
                    int row = m0 + wm + mi * 16 + quad * 4 + g;
                    rf2bb[(size_t)row * BDIM + colL] = mishf(acc1[mi][nj][g] + bs);
                }
            }
        }
    }
}

// ---------------- new_BB = mish(BB @ W_bbbb^T + b) + rf2bb[b] ----------------
// 1024 blocks x 64-row tiles; A (16KB) + W (32KB) both staged via coalesced gld16
// (pre-swizzled source); 48KB LDS -> 3 blocks/CU; one barrier; 32 MFMAs/wave.
__global__ void __launch_bounds__(256) k_newbb(
    const short* __restrict__ bbb,   // [65536,128] bf16
    const short* __restrict__ wb,    // [128,128]   bf16
    const float* __restrict__ bias,  // [128]
    const float* __restrict__ rf2bb, // [4096,128]  fp32
    float* __restrict__ out)         // [65536,128]
{
    __shared__ alignas(16) short At[64 * 128];
    __shared__ alignas(16) short Wt[128 * 128];
    int tid = threadIdx.x;
    int wave = tid >> 6, lane = tid & 63;
    int r = lane & 15, quad = lane >> 4;
    size_t m0 = (size_t)blockIdx.x * 64;

    int lrow = lane >> 4;     // 0..3
    int lslot = lane & 15;    // 16B slot within 256B row
    // stage W: wave w -> rows w*32 .. w*32+31 (8 issues of 4 rows)
    #pragma unroll
    for (int j = 0; j < 8; ++j) {
        int row = wave * 32 + j * 4 + lrow;
        int col = ((lslot ^ (row & 7)) << 3);   // pre-swizzled source column
        gld16(wb + (size_t)row * BDIM + col, &Wt[(wave * 32 + j * 4) * 128]);
    }
    // stage A: wave w -> rows w*16 .. w*16+15 (4 issues of 4 rows)
    #pragma unroll
    for (int j = 0; j < 4; ++j) {
        int row = wave * 16 + j * 4 + lrow;
        int col = ((lslot ^ (row & 7)) << 3);
        gld16(bbb + (m0 + row) * BDIM + col, &At[(wave * 16 + j * 4) * 128]);
    }

    floatx4 acc[8];
    #pragma unroll
    for (int j = 0; j < 8; ++j) acc[j] = floatx4{0.f,0.f,0.f,0.f};

    // per-wave rows are one batch: rf2bb row = m0/16 + wave
    size_t prow = (m0 >> 4) + wave;

    __syncthreads();   // drains gld16 -> tiles ready

    #pragma unroll
    for (int kc = 0; kc < 4; ++kc) {
        int sw = (((kc << 2) + quad) ^ (r & 7)) << 3;
        short8 a = *(const short8*)&At[(wave * 16 + r) * 128 + sw];
        #pragma unroll
        for (int nj = 0; nj < 8; ++nj) {
            short8 b = *(const short8*)&Wt[(nj * 16 + r) * 128 + sw];
            acc[nj] = MFMA(a, b, acc[nj]);
        }
    }

    #pragma unroll
    for (int nj = 0; nj < 8; ++nj) {
        int col = nj * 16 + r;
        float bs = bias[col];
        float pv = rf2bb[prow * BDIM + col];
        #pragma unroll
        for (int g = 0; g < 4; ++g) {
            size_t row = m0 + wave * 16 + quad * 4 + g;
            out[row * BDIM + col] = mishf(acc[nj][g] + bs) + pv;
        }
    }
}

extern "C" void kernel_launch(void* const* d_in, const int* in_sizes, int n_in,
                              void* d_out, int out_size, void* d_ws, size_t ws_size,
                              hipStream_t stream) {
    const float* BB    = (const float*)d_in[0];
    const float* RF    = (const float*)d_in[1];
    const float* Wrfbb = (const float*)d_in[2];
    const float* brfbb = (const float*)d_in[3];
    const float* Wrfrf = (const float*)d_in[4];
    const float* brfrf = (const float*)d_in[5];
    const float* Wbbrf = (const float*)d_in[6];
    const float* bbbrf = (const float*)d_in[7];
    const float* Wbbbb = (const float*)d_in[8];
    const float* bbbbb = (const float*)d_in[9];

    float* outBB = (float*)d_out;
    float* outRF = outBB + (size_t)NB * NG * BDIM;

    char* w = (char*)d_ws;
    short* mean_b  = (short*)(w);                  // 4096*128*2    = 1,048,576
    short* rf_b    = (short*)(w + 1048576);        // 4096*1024*2   = 8,388,608
    short* wrfrf_b = (short*)(w + 9437184);        // 1024*1024*2   = 2,097,152
    short* wrfbb_b = (short*)(w + 11534336);       // 128*1024*2    =   262,144
    short* wbbrf_b = (short*)(w + 11796480);       // 1024*128*2    =   262,144
    short* wbbbb_b = (short*)(w + 12058624);       // 128*128*2     =    32,768
    short* bb_b    = (short*)(w + 12091392);       // 65536*128*2   = 16,777,216
    float* rf2bb   = (float*)(w + 28868608);       // 4096*128*4    =  2,097,152
    // total ws: 30,965,760 B

    k_prep <<<512 + FLATB, 256, 0, stream>>>(BB, RF, Wrfrf, Wrfbb, Wbbrf, Wbbbb,
                                             bb_b, mean_b, rf_b, wrfrf_b, wrfbb_b,
                                             wbbrf_b, wbbbb_b);
    k_newrf<<<1152, 256, 0, stream>>>(rf_b, mean_b, wrfrf_b, brfrf, wbbrf_b, bbbrf,
                                      wrfbb_b, brfbb, outRF, rf2bb);
    k_newbb<<<1024, 256, 0, stream>>>(bb_b, wbbbb_b, bbbbb, rf2bb, outBB);
}